// Round 3
// baseline (521.445 us; speedup 1.0000x reference)
//
#include <hip/hip_runtime.h>
#include <hip/hip_bf16.h>

typedef unsigned short u16;
typedef __bf16 bf16x8 __attribute__((ext_vector_type(8)));
typedef float f32x4 __attribute__((ext_vector_type(4)));
typedef unsigned short u16x8 __attribute__((ext_vector_type(8)));
typedef unsigned short u16x4 __attribute__((ext_vector_type(4)));

__device__ __forceinline__ float bf2f(u16 u) {
  unsigned int x = ((unsigned int)u) << 16;
  return __builtin_bit_cast(float, x);
}
__device__ __forceinline__ u16 f2bf(float f) {
  unsigned int x = __builtin_bit_cast(unsigned int, f);
  x = x + 0x7FFFu + ((x >> 16) & 1u);
  return (u16)(x >> 16);
}

// async global->LDS, 16B per lane; LDS dest is wave-uniform base + lane*16.
__device__ __forceinline__ void gload_lds16(const u16* g, u16* l) {
  __builtin_amdgcn_global_load_lds(
      (const __attribute__((address_space(1))) unsigned int*)(unsigned long long)(uintptr_t)g,
      (__attribute__((address_space(3))) unsigned int*)(unsigned int)(uintptr_t)l,
      16, 0, 0);
}

// ---------------- cast X fp32 -> bf16 ----------------
__global__ __launch_bounds__(256) void cast_x_kernel(const float* __restrict__ X,
                                                     u16* __restrict__ Xb, long n) {
  long i = ((long)blockIdx.x * 256 + threadIdx.x) * 8;
  if (i >= n) return;
  float4 a = *reinterpret_cast<const float4*>(X + i);
  float4 b = *reinterpret_cast<const float4*>(X + i + 4);
  u16x8 o;
  o[0] = f2bf(a.x); o[1] = f2bf(a.y); o[2] = f2bf(a.z); o[3] = f2bf(a.w);
  o[4] = f2bf(b.x); o[5] = f2bf(b.y); o[6] = f2bf(b.z); o[7] = f2bf(b.w);
  *reinterpret_cast<u16x8*>(Xb + i) = o;
}

// ------- transpose+cast W (fp32 [1024][1024] -> bf16 [n][k], optional scale) -------
__global__ __launch_bounds__(256) void transpose_cast_w(const float* __restrict__ W,
                                                        u16* __restrict__ Wt, float scale) {
  __shared__ u16 t[64][72];
  const int r0 = blockIdx.y * 64;  // k dim
  const int c0 = blockIdx.x * 64;  // n dim
  const int tid = threadIdx.x;
#pragma unroll
  for (int i = 0; i < 4; ++i) {
    int slot = tid + 256 * i;
    int lr = slot >> 4;
    int lc4 = slot & 15;
    float4 v = *reinterpret_cast<const float4*>(W + (long)(r0 + lr) * 1024 + c0 + lc4 * 4);
    t[lr][lc4 * 4 + 0] = f2bf(v.x * scale);
    t[lr][lc4 * 4 + 1] = f2bf(v.y * scale);
    t[lr][lc4 * 4 + 2] = f2bf(v.z * scale);
    t[lr][lc4 * 4 + 3] = f2bf(v.w * scale);
  }
  __syncthreads();
#pragma unroll
  for (int i = 0; i < 2; ++i) {
    int slot = tid + 256 * i;
    int orow = slot >> 3;
    int oc = slot & 7;
    u16x8 o;
#pragma unroll
    for (int j = 0; j < 8; ++j) o[j] = t[oc * 8 + j][orow];
    *reinterpret_cast<u16x8*>(Wt + (long)(c0 + orow) * 1024 + r0 + oc * 8) = o;
  }
}

// ---------------- NT GEMM core: C[M][N] = sum_k A[m][k] * B[n][k] ----------------
// 128x128 tile, 4 waves (2x2 of 64x64), BK=64, global_load_lds width-16 staging.
// LDS: linear dest + PRE-SWIZZLED global source + XOR-swizzled ds_read (rule #21).
// MFMA operands SWAPPED (D rows = N-dim) so each lane owns 4 consecutive C
// columns -> vectorized stores. (V-quadrant of MODE 0 keeps normal order: its
// transposed store is already vectorized along M.)
// MODE 0: fused QKV. grid 1536. A=Xb[8192][1024], B=Wt[3072][1024].
//         Q,K -> bf16 [8192][1024]; V -> transposed Vt[b][1024][2048].
// MODE 1: S = Q K^T per batch. grid (16,16,4), skip bn>bm, bf16 out.
// MODE 2: O = P V per batch. grid (8,16,4), kEnd=m0+128, f32 out.
template <int MODE>
__global__ __launch_bounds__(256, 4) void gemm_nt(const u16* __restrict__ Ag,
                                                  const u16* __restrict__ Bg,
                                                  void* __restrict__ Cg,
                                                  int K, long sA, long sB, long sC) {
  int bm, bn, bz;
  if constexpr (MODE == 0) {
    const int id = blockIdx.x;           // 0..1535
    const int xcd = id & 7, j = id >> 3; // j: 0..191
    const int cx = xcd & 1, cy = xcd >> 1;
    bn = cx * 12 + j % 12;               // 0..23
    bm = cy * 16 + j / 12;               // 0..63
    bz = 0;
  } else if constexpr (MODE == 1) {
    const int id = blockIdx.y * 16 + blockIdx.x;  // 0..255
    const int xcd = id & 7, j = id >> 3;
    bn = j & 15;
    bm = (j >> 4) ? (15 - xcd) : xcd;    // rows (x,15-x): balanced triangle
    bz = blockIdx.z;
    if (bn > bm) return;
  } else {
    const int id = blockIdx.y * 8 + blockIdx.x;   // 0..127
    const int xcd = id & 7, j = id >> 3;
    bn = j & 7;
    bm = (j >> 3) ? (15 - xcd) : xcd;
    bz = blockIdx.z;
  }

  const u16* A = Ag + (long)bz * sA;
  const u16* B = Bg + (long)bz * sB;
  const int m0 = bm * 128, n0 = bn * 128;
  int kEnd = K;
  if constexpr (MODE == 2) kEnd = m0 + 128;  // causal k-limit

  __shared__ u16 ldsA[8192];
  __shared__ u16 ldsB[8192];

  const int tid = threadIdx.x;
  const int lane = tid & 63;
  const int wid = tid >> 6;
  const int wm = wid >> 1, wn = wid & 1;
  const int l16 = lane & 15, lh = lane >> 4;
  const int srow = lane >> 3;
  const int scol = ((lane & 7) ^ srow) * 8;  // pre-swizzled source column
  const int rsw = l16 & 7;                   // read-side swizzle key

  bool vblk = false;                         // V-quadrant: normal operand order
  if constexpr (MODE == 0) vblk = ((bn >> 3) == 2);

  f32x4 acc[4][4];
#pragma unroll
  for (int mi = 0; mi < 4; ++mi)
#pragma unroll
    for (int ni = 0; ni < 4; ++ni) acc[mi][ni] = (f32x4)(0.0f);

  for (int k0 = 0; k0 < kEnd; k0 += 64) {
    __syncthreads();  // all waves done reading LDS of previous tile
#pragma unroll
    for (int s = 0; s < 4; ++s) {
      const int seg = wid * 4 + s;           // 0..15 (1KB segments)
      const int row = seg * 8 + srow;        // 0..127
      gload_lds16(A + (long)(m0 + row) * K + k0 + scol, &ldsA[seg * 512]);
      gload_lds16(B + (long)(n0 + row) * K + k0 + scol, &ldsB[seg * 512]);
    }
    __syncthreads();  // drains vmcnt -> LDS tile ready
#pragma unroll
    for (int kk = 0; kk < 2; ++kk) {
      bf16x8 af[4], bfr[4];
#pragma unroll
      for (int mi = 0; mi < 4; ++mi)
        af[mi] = *reinterpret_cast<const bf16x8*>(
            &ldsA[(wm * 64 + mi * 16 + l16) * 64 + (((kk * 4 + lh) ^ rsw)) * 8]);
#pragma unroll
      for (int ni = 0; ni < 4; ++ni)
        bfr[ni] = *reinterpret_cast<const bf16x8*>(
            &ldsB[(wn * 64 + ni * 16 + l16) * 64 + (((kk * 4 + lh) ^ rsw)) * 8]);
      if (!vblk) {
#pragma unroll
        for (int mi = 0; mi < 4; ++mi)
#pragma unroll
          for (int ni = 0; ni < 4; ++ni)
            acc[mi][ni] = __builtin_amdgcn_mfma_f32_16x16x32_bf16(bfr[ni], af[mi], acc[mi][ni], 0, 0, 0);
      } else {
#pragma unroll
        for (int mi = 0; mi < 4; ++mi)
#pragma unroll
          for (int ni = 0; ni < 4; ++ni)
            acc[mi][ni] = __builtin_amdgcn_mfma_f32_16x16x32_bf16(af[mi], bfr[ni], acc[mi][ni], 0, 0, 0);
      }
    }
  }

  // Swapped layout: element C[m0+wm*64+mi*16+l16][n0+wn*64+ni*16+lh*4+r] = acc[mi][ni][r]
  if constexpr (MODE == 0) {
    const int z = bn >> 3;               // 0=Q, 1=K, 2=V
    const int colbase = (bn & 7) * 128;
    if (z < 2) {
      u16* C = (u16*)Cg + (long)z * 8388608;
      const long rown = (long)(m0 + wm * 64 + l16);
      const int coln = colbase + wn * 64 + lh * 4;
#pragma unroll
      for (int mi = 0; mi < 4; ++mi)
#pragma unroll
        for (int ni = 0; ni < 4; ++ni) {
          u16x4 o;
#pragma unroll
          for (int r = 0; r < 4; ++r) o[r] = f2bf(acc[mi][ni][r]);
          *reinterpret_cast<u16x4*>(&C[(rown + mi * 16) * 1024 + coln + ni * 16]) = o;
        }
    } else {
      // V (normal order): D row = M-dim. Vt[b][e][t], vector along t.
      u16* C = (u16*)Cg + 16777216;      // Vt base
      const int b = m0 >> 11;
      const int t0 = (m0 & 2047) + wm * 64 + lh * 4;
      const int e0 = colbase + wn * 64 + l16;
#pragma unroll
      for (int mi = 0; mi < 4; ++mi)
#pragma unroll
        for (int ni = 0; ni < 4; ++ni) {
          u16x4 o;
#pragma unroll
          for (int r = 0; r < 4; ++r) o[r] = f2bf(acc[mi][ni][r]);
          *reinterpret_cast<u16x4*>(
              &C[(long)b * 2097152 + (long)(e0 + ni * 16) * 2048 + t0 + mi * 16]) = o;
        }
    }
  } else if constexpr (MODE == 1) {
    u16* C = (u16*)Cg + (long)bz * sC;
    const long rown = (long)(m0 + wm * 64 + l16);
    const int coln = n0 + wn * 64 + lh * 4;
#pragma unroll
    for (int mi = 0; mi < 4; ++mi)
#pragma unroll
      for (int ni = 0; ni < 4; ++ni) {
        u16x4 o;
#pragma unroll
        for (int r = 0; r < 4; ++r) o[r] = f2bf(acc[mi][ni][r]);
        *reinterpret_cast<u16x4*>(&C[(rown + mi * 16) * 2048 + coln + ni * 16]) = o;
      }
  } else {
    float* C = (float*)Cg + (long)bz * sC;
    const long rown = (long)(m0 + wm * 64 + l16);
    const int coln = n0 + wn * 64 + lh * 4;
#pragma unroll
    for (int mi = 0; mi < 4; ++mi)
#pragma unroll
      for (int ni = 0; ni < 4; ++ni)
        *reinterpret_cast<f32x4*>(&C[(rown + mi * 16) * 1024 + coln + ni * 16]) =
            acc[mi][ni];
  }
}

// ---------------- causal row softmax, in-place on bf16 S ----------------
// One block per row; thread tid owns elements [tid*8, tid*8+8).
// Writes only k < round_up(len,128) — exactly the region PV's k-limit reads.
__global__ __launch_bounds__(256) void softmax_kernel(u16* __restrict__ S) {
  __shared__ float redm[4], reds[4];
  const int T = 2048;
  const long base = (long)blockIdx.x * T;
  const int q = blockIdx.x & (T - 1);
  const int len = q + 1;
  const int lenCeil = (len + 127) & ~127;
  const int tid = threadIdx.x, lane = tid & 63, wid = tid >> 6;
  u16* row = S + base;
  const int k0 = tid * 8;

  float v[8];
  if (k0 < len) {
    u16x8 x = *reinterpret_cast<const u16x8*>(row + k0);
#pragma unroll
    for (int j = 0; j < 8; ++j) v[j] = bf2f(x[j]);
  }
  float m = -1e30f;
#pragma unroll
  for (int j = 0; j < 8; ++j)
    if (k0 + j < len) m = fmaxf(m, v[j]);
#pragma unroll
  for (int o = 32; o > 0; o >>= 1) m = fmaxf(m, __shfl_xor(m, o));
  if (lane == 0) redm[wid] = m;
  __syncthreads();
  const float mx = fmaxf(fmaxf(redm[0], redm[1]), fmaxf(redm[2], redm[3]));

  float e[8], s = 0.0f;
#pragma unroll
  for (int j = 0; j < 8; ++j) {
    e[j] = (k0 + j < len) ? __expf(v[j] - mx) : 0.0f;
    s += e[j];
  }
#pragma unroll
  for (int o = 32; o > 0; o >>= 1) s += __shfl_xor(s, o);
  if (lane == 0) reds[wid] = s;
  __syncthreads();
  const float inv = 1.0f / (reds[0] + reds[1] + reds[2] + reds[3]);

  if (k0 < lenCeil) {
    u16x8 o;
#pragma unroll
    for (int j = 0; j < 8; ++j) o[j] = f2bf(e[j] * inv);
    *reinterpret_cast<u16x8*>(row + k0) = o;
  }
}

extern "C" void kernel_launch(void* const* d_in, const int* in_sizes, int n_in,
                              void* d_out, int out_size, void* d_ws, size_t ws_size,
                              hipStream_t stream) {
  const float* X  = (const float*)d_in[0];
  const float* Wq = (const float*)d_in[1];
  const float* Wk = (const float*)d_in[2];
  const float* Wv = (const float*)d_in[3];

  // workspace layout (u16 elements)
  u16* Xb = (u16*)d_ws;                 // 8192*1024
  u16* Wt = Xb + 8388608;               // 3*1024*1024 ([3072][1024]; Wq rows pre-scaled 1/32)
  u16* Qb = Wt + 3145728;               // 8192*1024
  u16* Kb = Qb + 8388608;               // 8192*1024
  u16* Vt = Kb + 8388608;               // [b][1024][2048]
  u16* S  = Vt + 8388608;               // [b][2048][2048]

  cast_x_kernel<<<4096, 256, 0, stream>>>(X, Xb, 8388608L);
  transpose_cast_w<<<dim3(16, 16), 256, 0, stream>>>(Wq, Wt,           1.0f / 32.0f);
  transpose_cast_w<<<dim3(16, 16), 256, 0, stream>>>(Wk, Wt + 1048576, 1.0f);
  transpose_cast_w<<<dim3(16, 16), 256, 0, stream>>>(Wv, Wt + 2097152, 1.0f);

  // fused QKV projection (V written transposed)
  gemm_nt<0><<<1536, 256, 0, stream>>>(Xb, Wt, Qb, 1024, 0L, 0L, 0L);

  // S = Q K^T per batch (Q pre-scaled)
  gemm_nt<1><<<dim3(16, 16, 4), 256, 0, stream>>>(
      Qb, Kb, S, 1024, 2097152L, 2097152L, 4194304L);

  softmax_kernel<<<8192, 256, 0, stream>>>(S);

  // O = P V per batch
  gemm_nt<2><<<dim3(8, 16, 4), 256, 0, stream>>>(
      S, Vt, (float*)d_out, 2048, 4194304L, 2097152L, 2097152L);
}

// Round 4
// 172.748 us; speedup vs baseline: 3.0185x; 3.0185x over previous
//
#include <hip/hip_runtime.h>
#include <hip/hip_bf16.h>

typedef unsigned short u16;
typedef __bf16 bf16x8 __attribute__((ext_vector_type(8)));
typedef float f32x4 __attribute__((ext_vector_type(4)));
typedef unsigned short u16x8 __attribute__((ext_vector_type(8)));
typedef unsigned short u16x4 __attribute__((ext_vector_type(4)));

__device__ __forceinline__ float bf2f(u16 u) {
  unsigned int x = ((unsigned int)u) << 16;
  return __builtin_bit_cast(float, x);
}
__device__ __forceinline__ u16 f2bf(float f) {
  unsigned int x = __builtin_bit_cast(unsigned int, f);
  x = x + 0x7FFFu + ((x >> 16) & 1u);
  return (u16)(x >> 16);
}

// async global->LDS, 16B per lane; LDS dest is wave-uniform base + lane*16.
__device__ __forceinline__ void gload_lds16(const u16* g, u16* l) {
  __builtin_amdgcn_global_load_lds(
      (const __attribute__((address_space(1))) unsigned int*)(unsigned long long)(uintptr_t)g,
      (__attribute__((address_space(3))) unsigned int*)(unsigned int)(uintptr_t)l,
      16, 0, 0);
}

// ---------------- cast X fp32 -> bf16 ----------------
__global__ __launch_bounds__(256) void cast_x_kernel(const float* __restrict__ X,
                                                     u16* __restrict__ Xb, long n) {
  long i = ((long)blockIdx.x * 256 + threadIdx.x) * 8;
  if (i >= n) return;
  float4 a = *reinterpret_cast<const float4*>(X + i);
  float4 b = *reinterpret_cast<const float4*>(X + i + 4);
  u16x8 o;
  o[0] = f2bf(a.x); o[1] = f2bf(a.y); o[2] = f2bf(a.z); o[3] = f2bf(a.w);
  o[4] = f2bf(b.x); o[5] = f2bf(b.y); o[6] = f2bf(b.z); o[7] = f2bf(b.w);
  *reinterpret_cast<u16x8*>(Xb + i) = o;
}

// ------- transpose+cast W (fp32 [1024][1024] -> bf16 [n][k], optional scale) -------
__global__ __launch_bounds__(256) void transpose_cast_w(const float* __restrict__ W,
                                                        u16* __restrict__ Wt, float scale) {
  __shared__ u16 t[64][72];
  const int r0 = blockIdx.y * 64;  // k dim
  const int c0 = blockIdx.x * 64;  // n dim
  const int tid = threadIdx.x;
#pragma unroll
  for (int i = 0; i < 4; ++i) {
    int slot = tid + 256 * i;
    int lr = slot >> 4;
    int lc4 = slot & 15;
    float4 v = *reinterpret_cast<const float4*>(W + (long)(r0 + lr) * 1024 + c0 + lc4 * 4);
    t[lr][lc4 * 4 + 0] = f2bf(v.x * scale);
    t[lr][lc4 * 4 + 1] = f2bf(v.y * scale);
    t[lr][lc4 * 4 + 2] = f2bf(v.z * scale);
    t[lr][lc4 * 4 + 3] = f2bf(v.w * scale);
  }
  __syncthreads();
#pragma unroll
  for (int i = 0; i < 2; ++i) {
    int slot = tid + 256 * i;
    int orow = slot >> 3;
    int oc = slot & 7;
    u16x8 o;
#pragma unroll
    for (int j = 0; j < 8; ++j) o[j] = t[oc * 8 + j][orow];
    *reinterpret_cast<u16x8*>(Wt + (long)(c0 + orow) * 1024 + r0 + oc * 8) = o;
  }
}

// ---------------- NT GEMM core: C[M][N] = sum_k A[m][k] * B[n][k] ----------------
// 128x128 tile, 4 waves (2x2 of 64x64), BK=64, global_load_lds width-16 staging.
// LDS: linear dest + PRE-SWIZZLED global source + XOR-swizzled ds_read (rule #21).
// MFMA operands SWAPPED (D rows = N-dim) so each lane owns 4 consecutive C
// columns -> vectorized stores. (V-quadrant of MODE 0 keeps normal order: its
// transposed store is already vectorized along M.)
// __launch_bounds__(256,2): min-waves 4 forced VGPR<=64 -> acc spill to scratch
// (r3: WRITE 49MB->1.45GB, 468us). 2 keeps ~76 VGPR, no spill.
// MODE 0: fused QKV. grid 1536. A=Xb[8192][1024], B=Wt[3072][1024].
//         Q,K -> bf16 [8192][1024]; V -> transposed Vt[b][1024][2048].
// MODE 1: S = Q K^T per batch. grid (16,16,4), skip bn>bm, bf16 out.
// MODE 2: O = P V per batch. grid (8,16,4), kEnd=m0+128, f32 out.
template <int MODE>
__global__ __launch_bounds__(256, 2) void gemm_nt(const u16* __restrict__ Ag,
                                                  const u16* __restrict__ Bg,
                                                  void* __restrict__ Cg,
                                                  int K, long sA, long sB, long sC) {
  int bm, bn, bz;
  if constexpr (MODE == 0) {
    const int id = blockIdx.x;           // 0..1535
    const int xcd = id & 7, j = id >> 3; // j: 0..191
    const int cx = xcd & 1, cy = xcd >> 1;
    bn = cx * 12 + j % 12;               // 0..23
    bm = cy * 16 + j / 12;               // 0..63
    bz = 0;
  } else if constexpr (MODE == 1) {
    const int id = blockIdx.y * 16 + blockIdx.x;  // 0..255
    const int xcd = id & 7, j = id >> 3;
    bn = j & 15;
    bm = (j >> 4) ? (15 - xcd) : xcd;    // rows (x,15-x): balanced triangle
    bz = blockIdx.z;
    if (bn > bm) return;
  } else {
    const int id = blockIdx.y * 8 + blockIdx.x;   // 0..127
    const int xcd = id & 7, j = id >> 3;
    bn = j & 7;
    bm = (j >> 3) ? (15 - xcd) : xcd;
    bz = blockIdx.z;
  }

  const u16* A = Ag + (long)bz * sA;
  const u16* B = Bg + (long)bz * sB;
  const int m0 = bm * 128, n0 = bn * 128;
  int kEnd = K;
  if constexpr (MODE == 2) kEnd = m0 + 128;  // causal k-limit

  __shared__ u16 ldsA[8192];
  __shared__ u16 ldsB[8192];

  const int tid = threadIdx.x;
  const int lane = tid & 63;
  const int wid = tid >> 6;
  const int wm = wid >> 1, wn = wid & 1;
  const int l16 = lane & 15, lh = lane >> 4;
  const int srow = lane >> 3;
  const int scol = ((lane & 7) ^ srow) * 8;  // pre-swizzled source column
  const int rsw = l16 & 7;                   // read-side swizzle key

  bool vblk = false;                         // V-quadrant: normal operand order
  if constexpr (MODE == 0) vblk = ((bn >> 3) == 2);

  f32x4 acc[4][4];
#pragma unroll
  for (int mi = 0; mi < 4; ++mi)
#pragma unroll
    for (int ni = 0; ni < 4; ++ni) acc[mi][ni] = (f32x4)(0.0f);

  for (int k0 = 0; k0 < kEnd; k0 += 64) {
    __syncthreads();  // all waves done reading LDS of previous tile
#pragma unroll
    for (int s = 0; s < 4; ++s) {
      const int seg = wid * 4 + s;           // 0..15 (1KB segments)
      const int row = seg * 8 + srow;        // 0..127
      gload_lds16(A + (long)(m0 + row) * K + k0 + scol, &ldsA[seg * 512]);
      gload_lds16(B + (long)(n0 + row) * K + k0 + scol, &ldsB[seg * 512]);
    }
    __syncthreads();  // drains vmcnt -> LDS tile ready
#pragma unroll
    for (int kk = 0; kk < 2; ++kk) {
      bf16x8 af[4], bfr[4];
#pragma unroll
      for (int mi = 0; mi < 4; ++mi)
        af[mi] = *reinterpret_cast<const bf16x8*>(
            &ldsA[(wm * 64 + mi * 16 + l16) * 64 + (((kk * 4 + lh) ^ rsw)) * 8]);
#pragma unroll
      for (int ni = 0; ni < 4; ++ni)
        bfr[ni] = *reinterpret_cast<const bf16x8*>(
            &ldsB[(wn * 64 + ni * 16 + l16) * 64 + (((kk * 4 + lh) ^ rsw)) * 8]);
      if (!vblk) {
#pragma unroll
        for (int mi = 0; mi < 4; ++mi)
#pragma unroll
          for (int ni = 0; ni < 4; ++ni)
            acc[mi][ni] = __builtin_amdgcn_mfma_f32_16x16x32_bf16(bfr[ni], af[mi], acc[mi][ni], 0, 0, 0);
      } else {
#pragma unroll
        for (int mi = 0; mi < 4; ++mi)
#pragma unroll
          for (int ni = 0; ni < 4; ++ni)
            acc[mi][ni] = __builtin_amdgcn_mfma_f32_16x16x32_bf16(af[mi], bfr[ni], acc[mi][ni], 0, 0, 0);
      }
    }
  }

  // Swapped layout: element C[m0+wm*64+mi*16+l16][n0+wn*64+ni*16+lh*4+r] = acc[mi][ni][r]
  if constexpr (MODE == 0) {
    const int z = bn >> 3;               // 0=Q, 1=K, 2=V
    const int colbase = (bn & 7) * 128;
    if (z < 2) {
      u16* C = (u16*)Cg + (long)z * 8388608;
      const long rown = (long)(m0 + wm * 64 + l16);
      const int coln = colbase + wn * 64 + lh * 4;
#pragma unroll
      for (int mi = 0; mi < 4; ++mi)
#pragma unroll
        for (int ni = 0; ni < 4; ++ni) {
          u16x4 o;
#pragma unroll
          for (int r = 0; r < 4; ++r) o[r] = f2bf(acc[mi][ni][r]);
          *reinterpret_cast<u16x4*>(&C[(rown + mi * 16) * 1024 + coln + ni * 16]) = o;
        }
    } else {
      // V (normal order): D row = M-dim. Vt[b][e][t], vector along t.
      u16* C = (u16*)Cg + 16777216;      // Vt base
      const int b = m0 >> 11;
      const int t0 = (m0 & 2047) + wm * 64 + lh * 4;
      const int e0 = colbase + wn * 64 + l16;
#pragma unroll
      for (int mi = 0; mi < 4; ++mi)
#pragma unroll
        for (int ni = 0; ni < 4; ++ni) {
          u16x4 o;
#pragma unroll
          for (int r = 0; r < 4; ++r) o[r] = f2bf(acc[mi][ni][r]);
          *reinterpret_cast<u16x4*>(
              &C[(long)b * 2097152 + (long)(e0 + ni * 16) * 2048 + t0 + mi * 16]) = o;
        }
    }
  } else if constexpr (MODE == 1) {
    u16* C = (u16*)Cg + (long)bz * sC;
    const long rown = (long)(m0 + wm * 64 + l16);
    const int coln = n0 + wn * 64 + lh * 4;
#pragma unroll
    for (int mi = 0; mi < 4; ++mi)
#pragma unroll
      for (int ni = 0; ni < 4; ++ni) {
        u16x4 o;
#pragma unroll
        for (int r = 0; r < 4; ++r) o[r] = f2bf(acc[mi][ni][r]);
        *reinterpret_cast<u16x4*>(&C[(rown + mi * 16) * 2048 + coln + ni * 16]) = o;
      }
  } else {
    float* C = (float*)Cg + (long)bz * sC;
    const long rown = (long)(m0 + wm * 64 + l16);
    const int coln = n0 + wn * 64 + lh * 4;
#pragma unroll
    for (int mi = 0; mi < 4; ++mi)
#pragma unroll
      for (int ni = 0; ni < 4; ++ni)
        *reinterpret_cast<f32x4*>(&C[(rown + mi * 16) * 1024 + coln + ni * 16]) =
            acc[mi][ni];
  }
}

// ---------------- causal row softmax, in-place on bf16 S ----------------
// One block per row; thread tid owns elements [tid*8, tid*8+8).
// Writes only k < round_up(len,128) — exactly the region PV's k-limit reads.
__global__ __launch_bounds__(256) void softmax_kernel(u16* __restrict__ S) {
  __shared__ float redm[4], reds[4];
  const int T = 2048;
  const long base = (long)blockIdx.x * T;
  const int q = blockIdx.x & (T - 1);
  const int len = q + 1;
  const int lenCeil = (len + 127) & ~127;
  const int tid = threadIdx.x, lane = tid & 63, wid = tid >> 6;
  u16* row = S + base;
  const int k0 = tid * 8;

  float v[8];
  if (k0 < len) {
    u16x8 x = *reinterpret_cast<const u16x8*>(row + k0);
#pragma unroll
    for (int j = 0; j < 8; ++j) v[j] = bf2f(x[j]);
  }
  float m = -1e30f;
#pragma unroll
  for (int j = 0; j < 8; ++j)
    if (k0 + j < len) m = fmaxf(m, v[j]);
#pragma unroll
  for (int o = 32; o > 0; o >>= 1) m = fmaxf(m, __shfl_xor(m, o));
  if (lane == 0) redm[wid] = m;
  __syncthreads();
  const float mx = fmaxf(fmaxf(redm[0], redm[1]), fmaxf(redm[2], redm[3]));

  float e[8], s = 0.0f;
#pragma unroll
  for (int j = 0; j < 8; ++j) {
    e[j] = (k0 + j < len) ? __expf(v[j] - mx) : 0.0f;
    s += e[j];
  }
#pragma unroll
  for (int o = 32; o > 0; o >>= 1) s += __shfl_xor(s, o);
  if (lane == 0) reds[wid] = s;
  __syncthreads();
  const float inv = 1.0f / (reds[0] + reds[1] + reds[2] + reds[3]);

  if (k0 < lenCeil) {
    u16x8 o;
#pragma unroll
    for (int j = 0; j < 8; ++j) o[j] = f2bf(e[j] * inv);
    *reinterpret_cast<u16x8*>(row + k0) = o;
  }
}

extern "C" void kernel_launch(void* const* d_in, const int* in_sizes, int n_in,
                              void* d_out, int out_size, void* d_ws, size_t ws_size,
                              hipStream_t stream) {
  const float* X  = (const float*)d_in[0];
  const float* Wq = (const float*)d_in[1];
  const float* Wk = (const float*)d_in[2];
  const float* Wv = (const float*)d_in[3];

  // workspace layout (u16 elements)
  u16* Xb = (u16*)d_ws;                 // 8192*1024
  u16* Wt = Xb + 8388608;               // 3*1024*1024 ([3072][1024]; Wq rows pre-scaled 1/32)
  u16* Qb = Wt + 3145728;               // 8192*1024
  u16* Kb = Qb + 8388608;               // 8192*1024
  u16* Vt = Kb + 8388608;               // [b][1024][2048]
  u16* S  = Vt + 8388608;               // [b][2048][2048]

  cast_x_kernel<<<4096, 256, 0, stream>>>(X, Xb, 8388608L);
  transpose_cast_w<<<dim3(16, 16), 256, 0, stream>>>(Wq, Wt,           1.0f / 32.0f);
  transpose_cast_w<<<dim3(16, 16), 256, 0, stream>>>(Wk, Wt + 1048576, 1.0f);
  transpose_cast_w<<<dim3(16, 16), 256, 0, stream>>>(Wv, Wt + 2097152, 1.0f);

  // fused QKV projection (V written transposed)
  gemm_nt<0><<<1536, 256, 0, stream>>>(Xb, Wt, Qb, 1024, 0L, 0L, 0L);

  // S = Q K^T per batch (Q pre-scaled)
  gemm_nt<1><<<dim3(16, 16, 4), 256, 0, stream>>>(
      Qb, Kb, S, 1024, 2097152L, 2097152L, 4194304L);

  softmax_kernel<<<8192, 256, 0, stream>>>(S);

  // O = P V per batch
  gemm_nt<2><<<dim3(8, 16, 4), 256, 0, stream>>>(
      S, Vt, (float*)d_out, 2048, 4194304L, 2097152L, 2097152L);
}

// Round 5
// 156.655 us; speedup vs baseline: 3.3286x; 1.1027x over previous
//
#include <hip/hip_runtime.h>
#include <hip/hip_bf16.h>

typedef unsigned short u16;
typedef __bf16 bf16x8 __attribute__((ext_vector_type(8)));
typedef float f32x4 __attribute__((ext_vector_type(4)));
typedef unsigned short u16x8 __attribute__((ext_vector_type(8)));
typedef unsigned short u16x4 __attribute__((ext_vector_type(4)));

__device__ __forceinline__ float bf2f(u16 u) {
  unsigned int x = ((unsigned int)u) << 16;
  return __builtin_bit_cast(float, x);
}
__device__ __forceinline__ u16 f2bf(float f) {
  unsigned int x = __builtin_bit_cast(unsigned int, f);
  x = x + 0x7FFFu + ((x >> 16) & 1u);
  return (u16)(x >> 16);
}

// async global->LDS, 16B per lane; LDS dest is wave-uniform base + lane*16.
__device__ __forceinline__ void gload_lds16(const u16* g, u16* l) {
  __builtin_amdgcn_global_load_lds(
      (const __attribute__((address_space(1))) unsigned int*)(unsigned long long)(uintptr_t)g,
      (__attribute__((address_space(3))) unsigned int*)(unsigned int)(uintptr_t)l,
      16, 0, 0);
}

// ---------------- cast X fp32 -> bf16 ----------------
__global__ __launch_bounds__(256) void cast_x_kernel(const float* __restrict__ X,
                                                     u16* __restrict__ Xb, long n) {
  long i = ((long)blockIdx.x * 256 + threadIdx.x) * 8;
  if (i >= n) return;
  float4 a = *reinterpret_cast<const float4*>(X + i);
  float4 b = *reinterpret_cast<const float4*>(X + i + 4);
  u16x8 o;
  o[0] = f2bf(a.x); o[1] = f2bf(a.y); o[2] = f2bf(a.z); o[3] = f2bf(a.w);
  o[4] = f2bf(b.x); o[5] = f2bf(b.y); o[6] = f2bf(b.z); o[7] = f2bf(b.w);
  *reinterpret_cast<u16x8*>(Xb + i) = o;
}

// ------- transpose+cast W (fp32 [1024][1024] -> bf16 [n][k], optional scale) -------
__global__ __launch_bounds__(256) void transpose_cast_w(const float* __restrict__ W,
                                                        u16* __restrict__ Wt, float scale) {
  __shared__ u16 t[64][72];
  const int r0 = blockIdx.y * 64;  // k dim
  const int c0 = blockIdx.x * 64;  // n dim
  const int tid = threadIdx.x;
#pragma unroll
  for (int i = 0; i < 4; ++i) {
    int slot = tid + 256 * i;
    int lr = slot >> 4;
    int lc4 = slot & 15;
    float4 v = *reinterpret_cast<const float4*>(W + (long)(r0 + lr) * 1024 + c0 + lc4 * 4);
    t[lr][lc4 * 4 + 0] = f2bf(v.x * scale);
    t[lr][lc4 * 4 + 1] = f2bf(v.y * scale);
    t[lr][lc4 * 4 + 2] = f2bf(v.z * scale);
    t[lr][lc4 * 4 + 3] = f2bf(v.w * scale);
  }
  __syncthreads();
#pragma unroll
  for (int i = 0; i < 2; ++i) {
    int slot = tid + 256 * i;
    int orow = slot >> 3;
    int oc = slot & 7;
    u16x8 o;
#pragma unroll
    for (int j = 0; j < 8; ++j) o[j] = t[oc * 8 + j][orow];
    *reinterpret_cast<u16x8*>(Wt + (long)(c0 + orow) * 1024 + r0 + oc * 8) = o;
  }
}

// ---------------- NT GEMM core: C[M][N] = sum_k A[m][k] * B[n][k] ----------------
// 128x128 tile, 4 waves (2x2 of 64x64), BK=64, global_load_lds width-16 staging.
// PIPELINE (r5): double-buffered LDS, ONE barrier per K-step; next tile's
// loads are issued right after the barrier and land during this tile's
// ds_read+MFMA. Race-free: in any barrier-to-barrier window, in-flight DMA
// writes target only buf^1 while ds_reads target buf[cur]; a buffer is
// re-staged only after the barrier following its last (lgkm-drained) reads.
// LDS: linear dest + PRE-SWIZZLED global source + XOR-swizzled ds_read.
// MFMA operands SWAPPED (D rows = N-dim) -> vectorized C stores (V-quadrant
// of MODE 0 keeps normal order; its transposed store vectorizes along M).
// __launch_bounds__(256,2): (256,4) forced VGPR<=64 -> acc scratch spill (r3).
// MODE 0: fused QKV. grid 1536. Q,K -> bf16 [8192][1024]; V -> Vt[b][1024][2048].
// MODE 1: S = Q K^T per batch. grid (16,16,4), skip bn>bm, bf16 out.
// MODE 2: O = P V per batch. grid (8,16,4), kEnd=m0+128, f32 out.
template <int MODE>
__global__ __launch_bounds__(256, 2) void gemm_nt(const u16* __restrict__ Ag,
                                                  const u16* __restrict__ Bg,
                                                  void* __restrict__ Cg,
                                                  int K, long sA, long sB, long sC) {
  int bm, bn, bz;
  if constexpr (MODE == 0) {
    const int id = blockIdx.x;           // 0..1535
    const int xcd = id & 7, j = id >> 3; // j: 0..191
    const int cx = xcd & 1, cy = xcd >> 1;
    bn = cx * 12 + j % 12;               // 0..23
    bm = cy * 16 + j / 12;               // 0..63
    bz = 0;
  } else if constexpr (MODE == 1) {
    const int id = blockIdx.y * 16 + blockIdx.x;  // 0..255
    const int xcd = id & 7, j = id >> 3;
    bn = j & 15;
    bm = (j >> 4) ? (15 - xcd) : xcd;    // rows (x,15-x): balanced triangle
    bz = blockIdx.z;
    if (bn > bm) return;
  } else {
    const int id = blockIdx.y * 8 + blockIdx.x;   // 0..127
    const int xcd = id & 7, j = id >> 3;
    bn = j & 7;
    bm = (j >> 3) ? (15 - xcd) : xcd;
    bz = blockIdx.z;
  }

  const u16* A = Ag + (long)bz * sA;
  const u16* B = Bg + (long)bz * sB;
  const int m0 = bm * 128, n0 = bn * 128;
  int kEnd = K;
  if constexpr (MODE == 2) kEnd = m0 + 128;  // causal k-limit

  __shared__ u16 ldsA[2][8192];
  __shared__ u16 ldsB[2][8192];

  const int tid = threadIdx.x;
  const int lane = tid & 63;
  const int wid = tid >> 6;
  const int wm = wid >> 1, wn = wid & 1;
  const int l16 = lane & 15, lh = lane >> 4;
  const int srow = lane >> 3;
  const int scol = ((lane & 7) ^ srow) * 8;  // pre-swizzled source column
  const int rsw = l16 & 7;                   // read-side swizzle key

  bool vblk = false;                         // V-quadrant: normal operand order
  if constexpr (MODE == 0) vblk = ((bn >> 3) == 2);

  f32x4 acc[4][4];
#pragma unroll
  for (int mi = 0; mi < 4; ++mi)
#pragma unroll
    for (int ni = 0; ni < 4; ++ni) acc[mi][ni] = (f32x4)(0.0f);

  // stage tile at k0 into buffer d (8 gload_lds16 per thread)
  auto stage = [&](int d, int k0) {
#pragma unroll
    for (int s = 0; s < 4; ++s) {
      const int seg = wid * 4 + s;           // 0..15 (1KB segments)
      const int row = seg * 8 + srow;        // 0..127
      gload_lds16(A + (long)(m0 + row) * K + k0 + scol, &ldsA[d][seg * 512]);
      gload_lds16(B + (long)(n0 + row) * K + k0 + scol, &ldsB[d][seg * 512]);
    }
  };

  stage(0, 0);                               // prologue
  int cur = 0;
  for (int k0 = 0; k0 < kEnd; k0 += 64) {
    __syncthreads();                         // vmcnt(0)+lgkmcnt(0)+barrier: buf[cur] ready,
                                             // buf[cur^1]'s old readers done
    if (k0 + 64 < kEnd) stage(cur ^ 1, k0 + 64);  // lands during compute below
#pragma unroll
    for (int kk = 0; kk < 2; ++kk) {
      bf16x8 af[4], bfr[4];
#pragma unroll
      for (int mi = 0; mi < 4; ++mi)
        af[mi] = *reinterpret_cast<const bf16x8*>(
            &ldsA[cur][(wm * 64 + mi * 16 + l16) * 64 + (((kk * 4 + lh) ^ rsw)) * 8]);
#pragma unroll
      for (int ni = 0; ni < 4; ++ni)
        bfr[ni] = *reinterpret_cast<const bf16x8*>(
            &ldsB[cur][(wn * 64 + ni * 16 + l16) * 64 + (((kk * 4 + lh) ^ rsw)) * 8]);
      if (!vblk) {
#pragma unroll
        for (int mi = 0; mi < 4; ++mi)
#pragma unroll
          for (int ni = 0; ni < 4; ++ni)
            acc[mi][ni] = __builtin_amdgcn_mfma_f32_16x16x32_bf16(bfr[ni], af[mi], acc[mi][ni], 0, 0, 0);
      } else {
#pragma unroll
        for (int mi = 0; mi < 4; ++mi)
#pragma unroll
          for (int ni = 0; ni < 4; ++ni)
            acc[mi][ni] = __builtin_amdgcn_mfma_f32_16x16x32_bf16(af[mi], bfr[ni], acc[mi][ni], 0, 0, 0);
      }
    }
    cur ^= 1;
  }

  // Swapped layout: element C[m0+wm*64+mi*16+l16][n0+wn*64+ni*16+lh*4+r] = acc[mi][ni][r]
  if constexpr (MODE == 0) {
    const int z = bn >> 3;               // 0=Q, 1=K, 2=V
    const int colbase = (bn & 7) * 128;
    if (z < 2) {
      u16* C = (u16*)Cg + (long)z * 8388608;
      const long rown = (long)(m0 + wm * 64 + l16);
      const int coln = colbase + wn * 64 + lh * 4;
#pragma unroll
      for (int mi = 0; mi < 4; ++mi)
#pragma unroll
        for (int ni = 0; ni < 4; ++ni) {
          u16x4 o;
#pragma unroll
          for (int r = 0; r < 4; ++r) o[r] = f2bf(acc[mi][ni][r]);
          *reinterpret_cast<u16x4*>(&C[(rown + mi * 16) * 1024 + coln + ni * 16]) = o;
        }
    } else {
      // V (normal order): D row = M-dim. Vt[b][e][t], vector along t.
      u16* C = (u16*)Cg + 16777216;      // Vt base
      const int b = m0 >> 11;
      const int t0 = (m0 & 2047) + wm * 64 + lh * 4;
      const int e0 = colbase + wn * 64 + l16;
#pragma unroll
      for (int mi = 0; mi < 4; ++mi)
#pragma unroll
        for (int ni = 0; ni < 4; ++ni) {
          u16x4 o;
#pragma unroll
          for (int r = 0; r < 4; ++r) o[r] = f2bf(acc[mi][ni][r]);
          *reinterpret_cast<u16x4*>(
              &C[(long)b * 2097152 + (long)(e0 + ni * 16) * 2048 + t0 + mi * 16]) = o;
        }
    }
  } else if constexpr (MODE == 1) {
    u16* C = (u16*)Cg + (long)bz * sC;
    const long rown = (long)(m0 + wm * 64 + l16);
    const int coln = n0 + wn * 64 + lh * 4;
#pragma unroll
    for (int mi = 0; mi < 4; ++mi)
#pragma unroll
      for (int ni = 0; ni < 4; ++ni) {
        u16x4 o;
#pragma unroll
        for (int r = 0; r < 4; ++r) o[r] = f2bf(acc[mi][ni][r]);
        *reinterpret_cast<u16x4*>(&C[(rown + mi * 16) * 2048 + coln + ni * 16]) = o;
      }
  } else {
    float* C = (float*)Cg + (long)bz * sC;
    const long rown = (long)(m0 + wm * 64 + l16);
    const int coln = n0 + wn * 64 + lh * 4;
#pragma unroll
    for (int mi = 0; mi < 4; ++mi)
#pragma unroll
      for (int ni = 0; ni < 4; ++ni)
        *reinterpret_cast<f32x4*>(&C[(rown + mi * 16) * 1024 + coln + ni * 16]) =
            acc[mi][ni];
  }
}

// ---------------- causal row softmax, in-place on bf16 S ----------------
// One block per row; thread tid owns elements [tid*8, tid*8+8).
// Writes only k < round_up(len,128) — exactly the region PV's k-limit reads.
__global__ __launch_bounds__(256) void softmax_kernel(u16* __restrict__ S) {
  __shared__ float redm[4], reds[4];
  const int T = 2048;
  const long base = (long)blockIdx.x * T;
  const int q = blockIdx.x & (T - 1);
  const int len = q + 1;
  const int lenCeil = (len + 127) & ~127;
  const int tid = threadIdx.x, lane = tid & 63, wid = tid >> 6;
  u16* row = S + base;
  const int k0 = tid * 8;

  float v[8];
  if (k0 < len) {
    u16x8 x = *reinterpret_cast<const u16x8*>(row + k0);
#pragma unroll
    for (int j = 0; j < 8; ++j) v[j] = bf2f(x[j]);
  }
  float m = -1e30f;
#pragma unroll
  for (int j = 0; j < 8; ++j)
    if (k0 + j < len) m = fmaxf(m, v[j]);
#pragma unroll
  for (int o = 32; o > 0; o >>= 1) m = fmaxf(m, __shfl_xor(m, o));
  if (lane == 0) redm[wid] = m;
  __syncthreads();
  const float mx = fmaxf(fmaxf(redm[0], redm[1]), fmaxf(redm[2], redm[3]));

  float e[8], s = 0.0f;
#pragma unroll
  for (int j = 0; j < 8; ++j) {
    e[j] = (k0 + j < len) ? __expf(v[j] - mx) : 0.0f;
    s += e[j];
  }
#pragma unroll
  for (int o = 32; o > 0; o >>= 1) s += __shfl_xor(s, o);
  if (lane == 0) reds[wid] = s;
  __syncthreads();
  const float inv = 1.0f / (reds[0] + reds[1] + reds[2] + reds[3]);

  if (k0 < lenCeil) {
    u16x8 o;
#pragma unroll
    for (int j = 0; j < 8; ++j) o[j] = f2bf(e[j] * inv);
    *reinterpret_cast<u16x8*>(row + k0) = o;
  }
}

extern "C" void kernel_launch(void* const* d_in, const int* in_sizes, int n_in,
                              void* d_out, int out_size, void* d_ws, size_t ws_size,
                              hipStream_t stream) {
  const float* X  = (const float*)d_in[0];
  const float* Wq = (const float*)d_in[1];
  const float* Wk = (const float*)d_in[2];
  const float* Wv = (const float*)d_in[3];

  // workspace layout (u16 elements)
  u16* Xb = (u16*)d_ws;                 // 8192*1024
  u16* Wt = Xb + 8388608;               // 3*1024*1024 ([3072][1024]; Wq rows pre-scaled 1/32)
  u16* Qb = Wt + 3145728;               // 8192*1024
  u16* Kb = Qb + 8388608;               // 8192*1024
  u16* Vt = Kb + 8388608;               // [b][1024][2048]
  u16* S  = Vt + 8388608;               // [b][2048][2048]

  cast_x_kernel<<<4096, 256, 0, stream>>>(X, Xb, 8388608L);
  transpose_cast_w<<<dim3(16, 16), 256, 0, stream>>>(Wq, Wt,           1.0f / 32.0f);
  transpose_cast_w<<<dim3(16, 16), 256, 0, stream>>>(Wk, Wt + 1048576, 1.0f);
  transpose_cast_w<<<dim3(16, 16), 256, 0, stream>>>(Wv, Wt + 2097152, 1.0f);

  // fused QKV projection (V written transposed)
  gemm_nt<0><<<1536, 256, 0, stream>>>(Xb, Wt, Qb, 1024, 0L, 0L, 0L);

  // S = Q K^T per batch (Q pre-scaled)
  gemm_nt<1><<<dim3(16, 16, 4), 256, 0, stream>>>(
      Qb, Kb, S, 1024, 2097152L, 2097152L, 4194304L);

  softmax_kernel<<<8192, 256, 0, stream>>>(S);

  // O = P V per batch
  gemm_nt<2><<<dim3(8, 16, 4), 256, 0, stream>>>(
      S, Vt, (float*)d_out, 2048, 4194304L, 2097152L, 2097152L);
}